// Round 1
// baseline (327.098 us; speedup 1.0000x reference)
//
#include <hip/hip_runtime.h>
#include <hip/hip_bf16.h>

// GraphFeatureExtractor: B=64, N=64, T=16, D=512
// out = person_features with [:, :, 15, :] replaced by 2-layer ST-GCN result.
//
// Pipeline (all on `stream`, serial order provides cross-kernel sync):
//   k_adj   : A_norm[b][n][m] = A/(rowsum+1e-6), fp32, 64x64 per batch
//   k_prep  : w1,w2 -> bf16; zero BN-stat accumulators
//   k_copy  : bulk copy of t != 15 slices (HBM-bound, ~240 MB)
//   k_agg   : Z[b][m][c] = sum_n A_norm[b][n][m] * X[b][n][c]   (fp32 VALU, out bf16)
//   k_gemm  : Y[r][o] = sum_c Z[r][c]*W[o][c] + bias[o]         (bf16 MFMA 16x16x32)
//             + per-column sum / sumsq via shuffle+LDS+atomics (BN stats)
//   k_norm  : h = relu(g*(y-mean)*rsqrt(var+eps)+beta) -> H1 or d_out t=15 slice

typedef __attribute__((ext_vector_type(8))) short short8;
typedef __attribute__((ext_vector_type(4))) float v4f;

#define DIST_THRESH 150.0f
#define ROW_EPS 1e-6f
#define BN_EPS 1e-5f

__device__ __forceinline__ ushort f2bf(float f) {
  union { __hip_bfloat16 h; ushort u; } cv;
  cv.h = __float2bfloat16(f);
  return cv.u;
}

// ---------------- adjacency ----------------
__global__ __launch_bounds__(64) void k_adj(const float* __restrict__ bb,
                                            float* __restrict__ An) {
  int b = blockIdx.x;
  int t = threadIdx.x;  // 64 threads = 64 rows
  __shared__ float cx[64], cy[64];
  float4 v = *(const float4*)&bb[(size_t)(b * 64 + t) * 4];
  cx[t] = v.x + 0.5f * v.z;
  cy[t] = v.y + 0.5f * v.w;
  __syncthreads();
  float mycx = cx[t], mycy = cy[t];
  float rs = 0.f;
  for (int m = 0; m < 64; ++m) {
    float dx = mycx - cx[m], dy = mycy - cy[m];
    float d = sqrtf(dx * dx + dy * dy);
    float a = (m == t) ? 1.0f : ((d < DIST_THRESH) ? 1.0f : 0.0f);
    rs += a;
  }
  float inv = 1.0f / (rs + ROW_EPS);
  float* row = An + (size_t)b * 4096 + (size_t)t * 64;
  for (int m = 0; m < 64; ++m) {
    float dx = mycx - cx[m], dy = mycy - cy[m];
    float d = sqrtf(dx * dx + dy * dy);
    float a = (m == t) ? 1.0f : ((d < DIST_THRESH) ? 1.0f : 0.0f);
    row[m] = a * inv;
  }
}

// ---------------- prep: w -> bf16, zero stats ----------------
__global__ __launch_bounds__(256) void k_prep(const float* __restrict__ w1,
                                              const float* __restrict__ w2,
                                              ushort* __restrict__ wb,
                                              float* __restrict__ stats) {
  int idx = blockIdx.x * 256 + threadIdx.x;  // grid 2048 -> 524288
  float v = (idx < 262144) ? w1[idx] : w2[idx - 262144];
  wb[idx] = f2bf(v);
  if (idx < 2048) stats[idx] = 0.f;
}

// ---------------- bulk copy (skip t==15 rows) ----------------
__global__ __launch_bounds__(256) void k_copy(const float4* __restrict__ in,
                                              float4* __restrict__ out) {
  size_t i = (size_t)blockIdx.x * 256 + threadIdx.x;  // grid 8192 -> 2M threads
#pragma unroll
  for (int j = 0; j < 4; ++j) {
    size_t idx = i + (size_t)j * 2097152;  // total 8388608 float4
    int tt = (int)((idx >> 7) & 15);       // 128 float4 per (b,n,t) row
    if (tt != 15) out[idx] = in[idx];
  }
}

// ---------------- aggregation: Z[b][m][c] = sum_n An[b][n][m]*X[b][n][c] ----------------
__global__ __launch_bounds__(256) void k_agg(const float* __restrict__ Xbase,
                                             int rowStride,
                                             const float* __restrict__ An,
                                             ushort* __restrict__ Z) {
  int b = blockIdx.x;        // 64
  int c0 = blockIdx.y * 128; // 4 column tiles
  __shared__ float Xs[64][128];  // 32 KB
  __shared__ float As[64][64];   // 16 KB
  int t = threadIdx.x;

  const float* xb = Xbase + (size_t)b * 64 * rowStride;
  for (int i = t; i < 2048; i += 256) {  // 64 rows x 32 float4
    int n = i >> 5, c4 = (i & 31) << 2;
    *(float4*)&Xs[n][c4] = *(const float4*)&xb[(size_t)n * rowStride + c0 + c4];
  }
  const float4* ab = (const float4*)(An + (size_t)b * 4096);
  for (int i = t; i < 1024; i += 256) ((float4*)As)[i] = ab[i];
  __syncthreads();

  int c4 = (t & 31) << 2;   // column group (4 floats)
  int m0 = (t >> 5) << 3;   // 8 output nodes per thread
  float4 acc[8];
#pragma unroll
  for (int i = 0; i < 8; ++i) acc[i] = make_float4(0.f, 0.f, 0.f, 0.f);

  for (int n = 0; n < 64; ++n) {
    float4 x = *(const float4*)&Xs[n][c4];
    float4 a0 = *(const float4*)&As[n][m0];
    float4 a1 = *(const float4*)&As[n][m0 + 4];
    float as[8] = {a0.x, a0.y, a0.z, a0.w, a1.x, a1.y, a1.z, a1.w};
#pragma unroll
    for (int i = 0; i < 8; ++i) {
      acc[i].x = fmaf(as[i], x.x, acc[i].x);
      acc[i].y = fmaf(as[i], x.y, acc[i].y);
      acc[i].z = fmaf(as[i], x.z, acc[i].z);
      acc[i].w = fmaf(as[i], x.w, acc[i].w);
    }
  }

  size_t zbase = (size_t)b * 64 * 512 + c0 + c4;
#pragma unroll
  for (int i = 0; i < 8; ++i) {
    int m = m0 + i;
    ushort4 zz;
    zz.x = f2bf(acc[i].x);
    zz.y = f2bf(acc[i].y);
    zz.z = f2bf(acc[i].z);
    zz.w = f2bf(acc[i].w);
    *(ushort4*)&Z[zbase + (size_t)m * 512] = zz;
  }
}

// ---------------- GEMM: Y[r][o] = sum_c Z[r][c]*W[o][c] + bias[o] ----------------
// tile 64(M) x 64(N), BK=32, 256 threads = 4 waves, each wave 16 rows x 64 cols
__global__ __launch_bounds__(256) void k_gemm(const ushort* __restrict__ Z,
                                              const ushort* __restrict__ W,
                                              const float* __restrict__ bias,
                                              float* __restrict__ Y,
                                              float* __restrict__ sum,
                                              float* __restrict__ sumsq) {
  __shared__ __align__(16) ushort Zs[64 * 40];  // pad 32->40 (80B rows, 16B-aligned frag reads)
  __shared__ __align__(16) ushort Ws[64 * 40];
  __shared__ float redS[4][64], redQ[4][64];

  int t = threadIdx.x;
  int r0 = blockIdx.x * 64;  // 64 row tiles
  int o0 = blockIdx.y * 64;  // 8 col tiles
  int wv = t >> 6, lane = t & 63;
  int m = lane & 15, q = lane >> 4;

  v4f acc[4];
#pragma unroll
  for (int nf = 0; nf < 4; ++nf) acc[nf] = (v4f){0.f, 0.f, 0.f, 0.f};

  int srow = t >> 2, scg = (t & 3) << 3;  // staging: row 0..63, 8-bf16 groups

  for (int ks = 0; ks < 16; ++ks) {
    int k0 = ks * 32;
    __syncthreads();
    uint4 zv = *(const uint4*)&Z[(size_t)(r0 + srow) * 512 + k0 + scg];
    uint4 wvv = *(const uint4*)&W[(size_t)(o0 + srow) * 512 + k0 + scg];
    *(uint4*)&Zs[srow * 40 + scg] = zv;
    *(uint4*)&Ws[srow * 40 + scg] = wvv;
    __syncthreads();

    short8 a = *(const short8*)&Zs[(wv * 16 + m) * 40 + q * 8];
#pragma unroll
    for (int nf = 0; nf < 4; ++nf) {
      short8 bfr = *(const short8*)&Ws[(nf * 16 + m) * 40 + q * 8];
      acc[nf] = __builtin_amdgcn_mfma_f32_16x16x32_bf16(a, bfr, acc[nf], 0, 0, 0);
    }
  }

  // epilogue: bias, store Y fp32, per-column BN partial sums
#pragma unroll
  for (int nf = 0; nf < 4; ++nf) {
    int col = o0 + nf * 16 + m;
    float bv = bias[col];
    float s = 0.f, s2 = 0.f;
#pragma unroll
    for (int reg = 0; reg < 4; ++reg) {
      int row = r0 + wv * 16 + q * 4 + reg;
      float y = acc[nf][reg] + bv;
      Y[(size_t)row * 512 + col] = y;
      s += y;
      s2 += y * y;
    }
    s += __shfl_xor(s, 16);
    s += __shfl_xor(s, 32);
    s2 += __shfl_xor(s2, 16);
    s2 += __shfl_xor(s2, 32);
    if (q == 0) {
      redS[wv][nf * 16 + m] = s;
      redQ[wv][nf * 16 + m] = s2;
    }
  }
  __syncthreads();
  if (t < 64) {
    float s = redS[0][t] + redS[1][t] + redS[2][t] + redS[3][t];
    float s2 = redQ[0][t] + redQ[1][t] + redQ[2][t] + redQ[3][t];
    atomicAdd(&sum[o0 + t], s);
    atomicAdd(&sumsq[o0 + t], s2);
  }
}

// ---------------- BN + relu ----------------
__global__ __launch_bounds__(256) void k_norm(const float* __restrict__ Y,
                                              const float* __restrict__ sum,
                                              const float* __restrict__ sumsq,
                                              const float* __restrict__ g,
                                              const float* __restrict__ beta,
                                              float* __restrict__ out,
                                              int lastSlice) {
  int idx = blockIdx.x * 256 + threadIdx.x;  // grid 2048 -> 524288 float4 groups
  int o = (idx & 127) << 2;
  int r = idx >> 7;
  float4 y = *(const float4*)&Y[(size_t)r * 512 + o];
  float4 sm = *(const float4*)&sum[o];
  float4 sq = *(const float4*)&sumsq[o];
  float4 gg = *(const float4*)&g[o];
  float4 bb = *(const float4*)&beta[o];
  const float inv = 1.0f / 4096.0f;
  float4 h;
  {
    float mean = sm.x * inv, var = sq.x * inv - mean * mean;
    h.x = fmaxf(gg.x * (y.x - mean) * rsqrtf(var + BN_EPS) + bb.x, 0.f);
  }
  {
    float mean = sm.y * inv, var = sq.y * inv - mean * mean;
    h.y = fmaxf(gg.y * (y.y - mean) * rsqrtf(var + BN_EPS) + bb.y, 0.f);
  }
  {
    float mean = sm.z * inv, var = sq.z * inv - mean * mean;
    h.z = fmaxf(gg.z * (y.z - mean) * rsqrtf(var + BN_EPS) + bb.z, 0.f);
  }
  {
    float mean = sm.w * inv, var = sq.w * inv - mean * mean;
    h.w = fmaxf(gg.w * (y.w - mean) * rsqrtf(var + BN_EPS) + bb.w, 0.f);
  }
  if (lastSlice)
    *(float4*)&out[((size_t)r * 16 + 15) * 512 + o] = h;
  else
    *(float4*)&out[(size_t)r * 512 + o] = h;
}

extern "C" void kernel_launch(void* const* d_in, const int* in_sizes, int n_in,
                              void* d_out, int out_size, void* d_ws, size_t ws_size,
                              hipStream_t stream) {
  const float* pf = (const float*)d_in[0];
  const float* bboxes = (const float*)d_in[1];
  const float* w1 = (const float*)d_in[2];
  const float* b1 = (const float*)d_in[3];
  const float* g1 = (const float*)d_in[4];
  const float* be1 = (const float*)d_in[5];
  const float* w2 = (const float*)d_in[6];
  const float* b2 = (const float*)d_in[7];
  const float* g2 = (const float*)d_in[8];
  const float* be2 = (const float*)d_in[9];
  float* out = (float*)d_out;

  // workspace layout (22 MB total)
  float* An = (float*)d_ws;                  // 262144 f32  (A_norm)
  ushort* wb = (ushort*)(An + 262144);       // 524288 bf16 (w1|w2)
  ushort* Zb = wb + 524288;                  // 2097152 bf16 (Z)
  float* Yb = (float*)(Zb + 2097152);        // 2097152 f32 (Y)
  float* H1 = Yb + 2097152;                  // 2097152 f32 (layer1 out)
  float* stats = H1 + 2097152;               // 2048 f32
  float* sum1 = stats;
  float* sq1 = stats + 512;
  float* sum2 = stats + 1024;
  float* sq2 = stats + 1536;

  k_adj<<<64, 64, 0, stream>>>(bboxes, An);
  k_prep<<<2048, 256, 0, stream>>>(w1, w2, wb, stats);
  k_copy<<<8192, 256, 0, stream>>>((const float4*)pf, (float4*)out);

  // layer 1: X = pf[:, :, 15, :] (base offset 15*512, row stride 16*512)
  k_agg<<<dim3(64, 4), 256, 0, stream>>>(pf + 7680, 8192, An, Zb);
  k_gemm<<<dim3(64, 8), 256, 0, stream>>>(Zb, wb, b1, Yb, sum1, sq1);
  k_norm<<<2048, 256, 0, stream>>>(Yb, sum1, sq1, g1, be1, H1, 0);

  // layer 2: X = H1 (row stride 512)
  k_agg<<<dim3(64, 4), 256, 0, stream>>>(H1, 512, An, Zb);
  k_gemm<<<dim3(64, 8), 256, 0, stream>>>(Zb, wb + 262144, b2, Yb, sum2, sq2);
  k_norm<<<2048, 256, 0, stream>>>(Yb, sum2, sq2, g2, be2, out, 1);
}

// Round 2
// 318.605 us; speedup vs baseline: 1.0267x; 1.0267x over previous
//
#include <hip/hip_runtime.h>
#include <hip/hip_bf16.h>

// GraphFeatureExtractor: B=64, N=64, T=16, D=512
// out = person_features with [:, :, 15, :] replaced by 2-layer ST-GCN result.
//
// Round 2: fused pipeline, 6 dispatches (was 9):
//   k_copy_prep : bulk copy (t!=15) + w1,w2 -> bf16 + zero BN stats   (fat kernel)
//   k_agg  x2   : inline adjacency from bboxes + [BN+relu on X for layer 2]
//                 Z[b][m][c] = sum_n A_norm[b][n][m] * X[b][n][c] -> bf16
//   k_gemm x2   : Y = Z*W^T + b (bf16 MFMA 16x16x32) + per-col sum/sumsq atomics
//   k_norm      : BN+relu of layer-2 Y -> d_out t=15 slice

typedef __attribute__((ext_vector_type(8))) short short8;
typedef __attribute__((ext_vector_type(4))) float v4f;

#define DIST_THRESH 150.0f
#define ROW_EPS 1e-6f
#define BN_EPS 1e-5f

__device__ __forceinline__ ushort f2bf(float f) {
  union { __hip_bfloat16 h; ushort u; } cv;
  cv.h = __float2bfloat16(f);
  return cv.u;
}

// ---------------- fat: bulk copy (skip t==15) + w->bf16 + zero stats ----------------
__global__ __launch_bounds__(256) void k_copy_prep(const float4* __restrict__ in,
                                                   float4* __restrict__ out,
                                                   const float* __restrict__ w1,
                                                   const float* __restrict__ w2,
                                                   ushort* __restrict__ wb,
                                                   float* __restrict__ stats) {
  int blk = blockIdx.x;
  int t = threadIdx.x;
  if (blk < 8192) {
    size_t i = (size_t)blk * 256 + t;
#pragma unroll
    for (int j = 0; j < 4; ++j) {
      size_t idx = i + (size_t)j * 2097152;  // total 8388608 float4 = 128 MB
      int tt = (int)((idx >> 7) & 15);       // 128 float4 per (b,n,t) row
      if (tt != 15) out[idx] = in[idx];
    }
  } else {
    int idx = (blk - 8192) * 256 + t;  // 0..524287
    float v = (idx < 262144) ? w1[idx] : w2[idx - 262144];
    wb[idx] = f2bf(v);
    if (idx < 2048) stats[idx] = 0.f;
  }
}

// ---------------- aggregation (+inline adjacency, +optional BN/relu on X) ----------------
// Z[b][m][c] = sum_n A_norm[b][n][m] * X[b][n][c]
__global__ __launch_bounds__(256) void k_agg(const float* __restrict__ Xbase,
                                             int rowStride,
                                             const float* __restrict__ bb,
                                             const float* __restrict__ stats,  // [sum(512)|sumsq(512)]
                                             const float* __restrict__ g,
                                             const float* __restrict__ beta,
                                             int applyBN,
                                             ushort* __restrict__ Z) {
  int b = blockIdx.x;         // 64
  int c0 = blockIdx.y * 128;  // 4 column tiles
  int t = threadIdx.x;
  __shared__ float Xs[64][128];  // 32 KB
  __shared__ float As[64][64];   // 16 KB  (A_norm[b], [n][m])
  __shared__ float cxs[64], cys[64];
  __shared__ float scaleS[128], shiftS[128];

  if (t < 64) {
    float4 v = *(const float4*)&bb[(size_t)(b * 64 + t) * 4];
    cxs[t] = v.x + 0.5f * v.z;
    cys[t] = v.y + 0.5f * v.w;
  }
  if (applyBN && t < 32) {
    int c = t * 4;  // local column in tile
    float4 sm = *(const float4*)&stats[c0 + c];
    float4 sq = *(const float4*)&stats[512 + c0 + c];
    float4 gg = *(const float4*)&g[c0 + c];
    float4 bt = *(const float4*)&beta[c0 + c];
    const float inv = 1.0f / 4096.0f;
    float mean, var, sc;
    mean = sm.x * inv; var = sq.x * inv - mean * mean; sc = gg.x * rsqrtf(var + BN_EPS);
    scaleS[c] = sc; shiftS[c] = bt.x - mean * sc;
    mean = sm.y * inv; var = sq.y * inv - mean * mean; sc = gg.y * rsqrtf(var + BN_EPS);
    scaleS[c + 1] = sc; shiftS[c + 1] = bt.y - mean * sc;
    mean = sm.z * inv; var = sq.z * inv - mean * mean; sc = gg.z * rsqrtf(var + BN_EPS);
    scaleS[c + 2] = sc; shiftS[c + 2] = bt.z - mean * sc;
    mean = sm.w * inv; var = sq.w * inv - mean * mean; sc = gg.w * rsqrtf(var + BN_EPS);
    scaleS[c + 3] = sc; shiftS[c + 3] = bt.w - mean * sc;
  }
  __syncthreads();

  // adjacency rows: thread t<64 computes normalized row n=t of A_norm[b]
  if (t < 64) {
    float mycx = cxs[t], mycy = cys[t];
    float rs = 0.f;
    for (int m = 0; m < 64; ++m) {
      float dx = mycx - cxs[m], dy = mycy - cys[m];
      float d = sqrtf(dx * dx + dy * dy);
      float a = (m == t) ? 1.0f : ((d < DIST_THRESH) ? 1.0f : 0.0f);
      rs += a;
    }
    float inv = 1.0f / (rs + ROW_EPS);
    for (int m = 0; m < 64; ++m) {
      float dx = mycx - cxs[m], dy = mycy - cys[m];
      float d = sqrtf(dx * dx + dy * dy);
      float a = (m == t) ? 1.0f : ((d < DIST_THRESH) ? 1.0f : 0.0f);
      As[t][m] = a * inv;
    }
  }

  // X tile load (+BN/relu for layer 2)
  const float* xb = Xbase + (size_t)b * 64 * rowStride;
  for (int i = t; i < 2048; i += 256) {  // 64 rows x 32 float4
    int n = i >> 5, c4 = (i & 31) << 2;
    float4 x = *(const float4*)&xb[(size_t)n * rowStride + c0 + c4];
    if (applyBN) {
      x.x = fmaxf(x.x * scaleS[c4] + shiftS[c4], 0.f);
      x.y = fmaxf(x.y * scaleS[c4 + 1] + shiftS[c4 + 1], 0.f);
      x.z = fmaxf(x.z * scaleS[c4 + 2] + shiftS[c4 + 2], 0.f);
      x.w = fmaxf(x.w * scaleS[c4 + 3] + shiftS[c4 + 3], 0.f);
    }
    *(float4*)&Xs[n][c4] = x;
  }
  __syncthreads();

  int c4 = (t & 31) << 2;   // column group (4 floats)
  int m0 = (t >> 5) << 3;   // 8 output nodes per thread
  float4 acc[8];
#pragma unroll
  for (int i = 0; i < 8; ++i) acc[i] = make_float4(0.f, 0.f, 0.f, 0.f);

  for (int n = 0; n < 64; ++n) {
    float4 x = *(const float4*)&Xs[n][c4];
    float4 a0 = *(const float4*)&As[n][m0];
    float4 a1 = *(const float4*)&As[n][m0 + 4];
    float as[8] = {a0.x, a0.y, a0.z, a0.w, a1.x, a1.y, a1.z, a1.w};
#pragma unroll
    for (int i = 0; i < 8; ++i) {
      acc[i].x = fmaf(as[i], x.x, acc[i].x);
      acc[i].y = fmaf(as[i], x.y, acc[i].y);
      acc[i].z = fmaf(as[i], x.z, acc[i].z);
      acc[i].w = fmaf(as[i], x.w, acc[i].w);
    }
  }

  size_t zbase = (size_t)b * 64 * 512 + c0 + c4;
#pragma unroll
  for (int i = 0; i < 8; ++i) {
    int m = m0 + i;
    ushort4 zz;
    zz.x = f2bf(acc[i].x);
    zz.y = f2bf(acc[i].y);
    zz.z = f2bf(acc[i].z);
    zz.w = f2bf(acc[i].w);
    *(ushort4*)&Z[zbase + (size_t)m * 512] = zz;
  }
}

// ---------------- GEMM: Y[r][o] = sum_c Z[r][c]*W[o][c] + bias[o] ----------------
// tile 64(M) x 64(N), BK=32, 256 threads = 4 waves, each wave 16 rows x 64 cols
__global__ __launch_bounds__(256) void k_gemm(const ushort* __restrict__ Z,
                                              const ushort* __restrict__ W,
                                              const float* __restrict__ bias,
                                              float* __restrict__ Y,
                                              float* __restrict__ sum,
                                              float* __restrict__ sumsq) {
  __shared__ __align__(16) ushort Zs[64 * 40];  // pad 32->40
  __shared__ __align__(16) ushort Ws[64 * 40];
  __shared__ float redS[4][64], redQ[4][64];

  int t = threadIdx.x;
  int r0 = blockIdx.x * 64;  // 64 row tiles
  int o0 = blockIdx.y * 64;  // 8 col tiles
  int wv = t >> 6, lane = t & 63;
  int m = lane & 15, q = lane >> 4;

  v4f acc[4];
#pragma unroll
  for (int nf = 0; nf < 4; ++nf) acc[nf] = (v4f){0.f, 0.f, 0.f, 0.f};

  int srow = t >> 2, scg = (t & 3) << 3;  // staging: row 0..63, 8-bf16 groups

  for (int ks = 0; ks < 16; ++ks) {
    int k0 = ks * 32;
    __syncthreads();
    uint4 zv = *(const uint4*)&Z[(size_t)(r0 + srow) * 512 + k0 + scg];
    uint4 wvv = *(const uint4*)&W[(size_t)(o0 + srow) * 512 + k0 + scg];
    *(uint4*)&Zs[srow * 40 + scg] = zv;
    *(uint4*)&Ws[srow * 40 + scg] = wvv;
    __syncthreads();

    short8 a = *(const short8*)&Zs[(wv * 16 + m) * 40 + q * 8];
#pragma unroll
    for (int nf = 0; nf < 4; ++nf) {
      short8 bfr = *(const short8*)&Ws[(nf * 16 + m) * 40 + q * 8];
      acc[nf] = __builtin_amdgcn_mfma_f32_16x16x32_bf16(a, bfr, acc[nf], 0, 0, 0);
    }
  }

  // epilogue: bias, store Y fp32, per-column BN partial sums
#pragma unroll
  for (int nf = 0; nf < 4; ++nf) {
    int col = o0 + nf * 16 + m;
    float bv = bias[col];
    float s = 0.f, s2 = 0.f;
#pragma unroll
    for (int reg = 0; reg < 4; ++reg) {
      int row = r0 + wv * 16 + q * 4 + reg;
      float y = acc[nf][reg] + bv;
      Y[(size_t)row * 512 + col] = y;
      s += y;
      s2 += y * y;
    }
    s += __shfl_xor(s, 16);
    s += __shfl_xor(s, 32);
    s2 += __shfl_xor(s2, 16);
    s2 += __shfl_xor(s2, 32);
    if (q == 0) {
      redS[wv][nf * 16 + m] = s;
      redQ[wv][nf * 16 + m] = s2;
    }
  }
  __syncthreads();
  if (t < 64) {
    float s = redS[0][t] + redS[1][t] + redS[2][t] + redS[3][t];
    float s2 = redQ[0][t] + redQ[1][t] + redQ[2][t] + redQ[3][t];
    atomicAdd(&sum[o0 + t], s);
    atomicAdd(&sumsq[o0 + t], s2);
  }
}

// ---------------- final BN + relu -> t=15 slice of d_out ----------------
__global__ __launch_bounds__(256) void k_norm(const float* __restrict__ Y,
                                              const float* __restrict__ sum,
                                              const float* __restrict__ sumsq,
                                              const float* __restrict__ g,
                                              const float* __restrict__ beta,
                                              float* __restrict__ out) {
  int idx = blockIdx.x * 256 + threadIdx.x;  // 524288 float4 groups
  int o = (idx & 127) << 2;
  int r = idx >> 7;
  float4 y = *(const float4*)&Y[(size_t)r * 512 + o];
  float4 sm = *(const float4*)&sum[o];
  float4 sq = *(const float4*)&sumsq[o];
  float4 gg = *(const float4*)&g[o];
  float4 bb = *(const float4*)&beta[o];
  const float inv = 1.0f / 4096.0f;
  float4 h;
  {
    float mean = sm.x * inv, var = sq.x * inv - mean * mean;
    h.x = fmaxf(gg.x * (y.x - mean) * rsqrtf(var + BN_EPS) + bb.x, 0.f);
  }
  {
    float mean = sm.y * inv, var = sq.y * inv - mean * mean;
    h.y = fmaxf(gg.y * (y.y - mean) * rsqrtf(var + BN_EPS) + bb.y, 0.f);
  }
  {
    float mean = sm.z * inv, var = sq.z * inv - mean * mean;
    h.z = fmaxf(gg.z * (y.z - mean) * rsqrtf(var + BN_EPS) + bb.z, 0.f);
  }
  {
    float mean = sm.w * inv, var = sq.w * inv - mean * mean;
    h.w = fmaxf(gg.w * (y.w - mean) * rsqrtf(var + BN_EPS) + bb.w, 0.f);
  }
  *(float4*)&out[((size_t)r * 16 + 15) * 512 + o] = h;
}

extern "C" void kernel_launch(void* const* d_in, const int* in_sizes, int n_in,
                              void* d_out, int out_size, void* d_ws, size_t ws_size,
                              hipStream_t stream) {
  const float* pf = (const float*)d_in[0];
  const float* bboxes = (const float*)d_in[1];
  const float* w1 = (const float*)d_in[2];
  const float* b1 = (const float*)d_in[3];
  const float* g1 = (const float*)d_in[4];
  const float* be1 = (const float*)d_in[5];
  const float* w2 = (const float*)d_in[6];
  const float* b2 = (const float*)d_in[7];
  const float* g2 = (const float*)d_in[8];
  const float* be2 = (const float*)d_in[9];
  float* out = (float*)d_out;

  // workspace layout (~13 MB)
  ushort* wb = (ushort*)d_ws;           // 524288 bf16 (w1|w2)
  ushort* Zb = wb + 524288;             // 2097152 bf16 (Z)
  float* Yb = (float*)(Zb + 2097152);   // 2097152 f32 (Y, reused both layers)
  float* stats = Yb + 2097152;          // 2048 f32: [sum1|sq1|sum2|sq2]
  float* sum1 = stats;
  float* sq1 = stats + 512;
  float* sum2 = stats + 1024;
  float* sq2 = stats + 1536;

  // 1: copy + w->bf16 + zero stats
  k_copy_prep<<<10240, 256, 0, stream>>>((const float4*)pf, (float4*)out, w1, w2, wb, stats);

  // layer 1: X = pf[:, :, 15, :] (base offset 15*512, row stride 16*512)
  k_agg<<<dim3(64, 4), 256, 0, stream>>>(pf + 7680, 8192, bboxes, stats, g1, be1, 0, Zb);
  k_gemm<<<dim3(64, 8), 256, 0, stream>>>(Zb, wb, b1, Yb, sum1, sq1);

  // layer 2: X = BN1(Yb) inline (stats1 final after gemm1 dispatch boundary)
  k_agg<<<dim3(64, 4), 256, 0, stream>>>(Yb, 512, bboxes, stats, g1, be1, 1, Zb);
  k_gemm<<<dim3(64, 8), 256, 0, stream>>>(Zb, wb + 262144, b2, Yb, sum2, sq2);

  // final BN -> out t=15 slice
  k_norm<<<2048, 256, 0, stream>>>(Yb, sum2, sq2, g2, be2, out);
}

// Round 3
// 295.972 us; speedup vs baseline: 1.1052x; 1.0765x over previous
//
#include <hip/hip_runtime.h>
#include <hip/hip_bf16.h>

// GraphFeatureExtractor: B=64, N=64, T=16, D=512
// out = person_features with [:, :, 15, :] replaced by 2-layer ST-GCN result.
//
// Round 3:
//   - k_copy_prep: DENSE branch-free copy (t=15 rows get overwritten by k_norm
//     later in stream order). 4 batched loads -> 4 stores per thread so the
//     compiler keeps 4 loads in flight (round-2 counter evidence: predicated
//     copy ran at 2.3 TB/s = latency-bound; fillBuffer hits 6.6 TB/s).
//   - k_agg: adjacency build parallelized across all 256 threads (was 1 wave
//     serial while 3 waves idled); X-tile load overlapped with A-build.
//   - k_gemm: software prefetch of next K-tile during MFMA phase.

typedef __attribute__((ext_vector_type(8))) short short8;
typedef __attribute__((ext_vector_type(4))) float v4f;

#define DIST_THRESH 150.0f
#define ROW_EPS 1e-6f
#define BN_EPS 1e-5f

__device__ __forceinline__ ushort f2bf(float f) {
  union { __hip_bfloat16 h; ushort u; } cv;
  cv.h = __float2bfloat16(f);
  return cv.u;
}

// ---------------- fat: dense bulk copy + w->bf16 + zero stats ----------------
__global__ __launch_bounds__(256) void k_copy_prep(const float4* __restrict__ in,
                                                   float4* __restrict__ out,
                                                   const float* __restrict__ w1,
                                                   const float* __restrict__ w2,
                                                   ushort* __restrict__ wb,
                                                   float* __restrict__ stats) {
  int blk = blockIdx.x;
  int t = threadIdx.x;
  if (blk < 8192) {
    // dense copy: 8192 blocks x 1024 float4 = 8388608 float4 = 128 MB
    size_t base = (size_t)blk * 1024 + t;
    float4 r0 = in[base];
    float4 r1 = in[base + 256];
    float4 r2 = in[base + 512];
    float4 r3 = in[base + 768];
    out[base] = r0;
    out[base + 256] = r1;
    out[base + 512] = r2;
    out[base + 768] = r3;
  } else {
    int idx = (blk - 8192) * 256 + t;  // 0..524287
    float v = (idx < 262144) ? w1[idx] : w2[idx - 262144];
    wb[idx] = f2bf(v);
    if (idx < 2048) stats[idx] = 0.f;
  }
}

// ---------------- aggregation (+inline adjacency, +optional BN/relu on X) ----------------
// Z[b][m][c] = sum_n A_norm[b][n][m] * X[b][n][c]
__global__ __launch_bounds__(256) void k_agg(const float* __restrict__ Xbase,
                                             int rowStride,
                                             const float* __restrict__ bb,
                                             const float* __restrict__ stats,  // [sum(512)|sumsq(512)]
                                             const float* __restrict__ g,
                                             const float* __restrict__ beta,
                                             int applyBN,
                                             ushort* __restrict__ Z) {
  int b = blockIdx.x;         // 64
  int c0 = blockIdx.y * 128;  // 4 column tiles
  int t = threadIdx.x;
  __shared__ float Xs[64][128];  // 32 KB
  __shared__ float As[64][64];   // 16 KB  (A_norm[b], [n][m])
  __shared__ float cxs[64], cys[64];
  __shared__ float scaleS[128], shiftS[128];
  __shared__ float rsum[64][4];
  __shared__ float invr[64];

  if (t < 64) {
    float4 v = *(const float4*)&bb[(size_t)(b * 64 + t) * 4];
    cxs[t] = v.x + 0.5f * v.z;
    cys[t] = v.y + 0.5f * v.w;
  }
  if (applyBN && t < 32) {
    int c = t * 4;  // local column in tile
    float4 sm = *(const float4*)&stats[c0 + c];
    float4 sq = *(const float4*)&stats[512 + c0 + c];
    float4 gg = *(const float4*)&g[c0 + c];
    float4 bt = *(const float4*)&beta[c0 + c];
    const float inv = 1.0f / 4096.0f;
    float mean, var, sc;
    mean = sm.x * inv; var = sq.x * inv - mean * mean; sc = gg.x * rsqrtf(var + BN_EPS);
    scaleS[c] = sc; shiftS[c] = bt.x - mean * sc;
    mean = sm.y * inv; var = sq.y * inv - mean * mean; sc = gg.y * rsqrtf(var + BN_EPS);
    scaleS[c + 1] = sc; shiftS[c + 1] = bt.y - mean * sc;
    mean = sm.z * inv; var = sq.z * inv - mean * mean; sc = gg.z * rsqrtf(var + BN_EPS);
    scaleS[c + 2] = sc; shiftS[c + 2] = bt.z - mean * sc;
    mean = sm.w * inv; var = sq.w * inv - mean * mean; sc = gg.w * rsqrtf(var + BN_EPS);
    scaleS[c + 3] = sc; shiftS[c + 3] = bt.w - mean * sc;
  }
  __syncthreads();

  // parallel adjacency: thread t owns row an = t>>2, 16-col segment aq = t&3
  int an = t >> 2, aq = t & 3;
  float av[16];
  {
    float mycx = cxs[an], mycy = cys[an];
    float ps = 0.f;
#pragma unroll
    for (int j = 0; j < 16; ++j) {
      int m = aq * 16 + j;
      float dx = mycx - cxs[m], dy = mycy - cys[m];
      float d = sqrtf(dx * dx + dy * dy);
      float a = (m == an) ? 1.0f : ((d < DIST_THRESH) ? 1.0f : 0.0f);
      av[j] = a;
      ps += a;
    }
    rsum[an][aq] = ps;
  }

  // X tile load (+BN/relu for layer 2) — overlapped with A-build
  const float* xb = Xbase + (size_t)b * 64 * rowStride;
  for (int i = t; i < 2048; i += 256) {  // 64 rows x 32 float4
    int n = i >> 5, c4 = (i & 31) << 2;
    float4 x = *(const float4*)&xb[(size_t)n * rowStride + c0 + c4];
    if (applyBN) {
      x.x = fmaxf(x.x * scaleS[c4] + shiftS[c4], 0.f);
      x.y = fmaxf(x.y * scaleS[c4 + 1] + shiftS[c4 + 1], 0.f);
      x.z = fmaxf(x.z * scaleS[c4 + 2] + shiftS[c4 + 2], 0.f);
      x.w = fmaxf(x.w * scaleS[c4 + 3] + shiftS[c4 + 3], 0.f);
    }
    *(float4*)&Xs[n][c4] = x;
  }
  __syncthreads();

  if (t < 64)
    invr[t] = 1.0f / (rsum[t][0] + rsum[t][1] + rsum[t][2] + rsum[t][3] + ROW_EPS);
  __syncthreads();

  {
    float iv = invr[an];
#pragma unroll
    for (int j = 0; j < 16; ++j) As[an][aq * 16 + j] = av[j] * iv;
  }
  __syncthreads();

  int c4 = (t & 31) << 2;   // column group (4 floats)
  int m0 = (t >> 5) << 3;   // 8 output nodes per thread
  float4 acc[8];
#pragma unroll
  for (int i = 0; i < 8; ++i) acc[i] = make_float4(0.f, 0.f, 0.f, 0.f);

  for (int n = 0; n < 64; ++n) {
    float4 x = *(const float4*)&Xs[n][c4];
    float4 a0 = *(const float4*)&As[n][m0];
    float4 a1 = *(const float4*)&As[n][m0 + 4];
    float as[8] = {a0.x, a0.y, a0.z, a0.w, a1.x, a1.y, a1.z, a1.w};
#pragma unroll
    for (int i = 0; i < 8; ++i) {
      acc[i].x = fmaf(as[i], x.x, acc[i].x);
      acc[i].y = fmaf(as[i], x.y, acc[i].y);
      acc[i].z = fmaf(as[i], x.z, acc[i].z);
      acc[i].w = fmaf(as[i], x.w, acc[i].w);
    }
  }

  size_t zbase = (size_t)b * 64 * 512 + c0 + c4;
#pragma unroll
  for (int i = 0; i < 8; ++i) {
    int m = m0 + i;
    ushort4 zz;
    zz.x = f2bf(acc[i].x);
    zz.y = f2bf(acc[i].y);
    zz.z = f2bf(acc[i].z);
    zz.w = f2bf(acc[i].w);
    *(ushort4*)&Z[zbase + (size_t)m * 512] = zz;
  }
}

// ---------------- GEMM: Y[r][o] = sum_c Z[r][c]*W[o][c] + bias[o] ----------------
// tile 64(M) x 64(N), BK=32, 256 threads = 4 waves, each wave 16 rows x 64 cols
__global__ __launch_bounds__(256) void k_gemm(const ushort* __restrict__ Z,
                                              const ushort* __restrict__ W,
                                              const float* __restrict__ bias,
                                              float* __restrict__ Y,
                                              float* __restrict__ sum,
                                              float* __restrict__ sumsq) {
  __shared__ __align__(16) ushort Zs[64 * 40];  // pad 32->40
  __shared__ __align__(16) ushort Ws[64 * 40];
  __shared__ float redS[4][64], redQ[4][64];

  int t = threadIdx.x;
  int r0 = blockIdx.x * 64;  // 64 row tiles
  int o0 = blockIdx.y * 64;  // 8 col tiles
  int wv = t >> 6, lane = t & 63;
  int m = lane & 15, q = lane >> 4;

  v4f acc[4];
#pragma unroll
  for (int nf = 0; nf < 4; ++nf) acc[nf] = (v4f){0.f, 0.f, 0.f, 0.f};

  int srow = t >> 2, scg = (t & 3) << 3;  // staging: row 0..63, 8-bf16 groups
  const ushort* zp = &Z[(size_t)(r0 + srow) * 512 + scg];
  const ushort* wp = &W[(size_t)(o0 + srow) * 512 + scg];

  // prefetch first tile
  uint4 zv = *(const uint4*)zp;
  uint4 wvv = *(const uint4*)wp;

  for (int ks = 0; ks < 16; ++ks) {
    __syncthreads();
    *(uint4*)&Zs[srow * 40 + scg] = zv;
    *(uint4*)&Ws[srow * 40 + scg] = wvv;
    __syncthreads();

    if (ks < 15) {  // prefetch next tile; latency hides under ds_read+MFMA
      zv = *(const uint4*)(zp + (ks + 1) * 32);
      wvv = *(const uint4*)(wp + (ks + 1) * 32);
    }

    short8 a = *(const short8*)&Zs[(wv * 16 + m) * 40 + q * 8];
#pragma unroll
    for (int nf = 0; nf < 4; ++nf) {
      short8 bfr = *(const short8*)&Ws[(nf * 16 + m) * 40 + q * 8];
      acc[nf] = __builtin_amdgcn_mfma_f32_16x16x32_bf16(a, bfr, acc[nf], 0, 0, 0);
    }
  }

  // epilogue: bias, store Y fp32, per-column BN partial sums
#pragma unroll
  for (int nf = 0; nf < 4; ++nf) {
    int col = o0 + nf * 16 + m;
    float bv = bias[col];
    float s = 0.f, s2 = 0.f;
#pragma unroll
    for (int reg = 0; reg < 4; ++reg) {
      int row = r0 + wv * 16 + q * 4 + reg;
      float y = acc[nf][reg] + bv;
      Y[(size_t)row * 512 + col] = y;
      s += y;
      s2 += y * y;
    }
    s += __shfl_xor(s, 16);
    s += __shfl_xor(s, 32);
    s2 += __shfl_xor(s2, 16);
    s2 += __shfl_xor(s2, 32);
    if (q == 0) {
      redS[wv][nf * 16 + m] = s;
      redQ[wv][nf * 16 + m] = s2;
    }
  }
  __syncthreads();
  if (t < 64) {
    float s = redS[0][t] + redS[1][t] + redS[2][t] + redS[3][t];
    float s2 = redQ[0][t] + redQ[1][t] + redQ[2][t] + redQ[3][t];
    atomicAdd(&sum[o0 + t], s);
    atomicAdd(&sumsq[o0 + t], s2);
  }
}

// ---------------- final BN + relu -> t=15 slice of d_out ----------------
__global__ __launch_bounds__(256) void k_norm(const float* __restrict__ Y,
                                              const float* __restrict__ sum,
                                              const float* __restrict__ sumsq,
                                              const float* __restrict__ g,
                                              const float* __restrict__ beta,
                                              float* __restrict__ out) {
  int idx = blockIdx.x * 256 + threadIdx.x;  // 524288 float4 groups
  int o = (idx & 127) << 2;
  int r = idx >> 7;
  float4 y = *(const float4*)&Y[(size_t)r * 512 + o];
  float4 sm = *(const float4*)&sum[o];
  float4 sq = *(const float4*)&sumsq[o];
  float4 gg = *(const float4*)&g[o];
  float4 bb = *(const float4*)&beta[o];
  const float inv = 1.0f / 4096.0f;
  float4 h;
  {
    float mean = sm.x * inv, var = sq.x * inv - mean * mean;
    h.x = fmaxf(gg.x * (y.x - mean) * rsqrtf(var + BN_EPS) + bb.x, 0.f);
  }
  {
    float mean = sm.y * inv, var = sq.y * inv - mean * mean;
    h.y = fmaxf(gg.y * (y.y - mean) * rsqrtf(var + BN_EPS) + bb.y, 0.f);
  }
  {
    float mean = sm.z * inv, var = sq.z * inv - mean * mean;
    h.z = fmaxf(gg.z * (y.z - mean) * rsqrtf(var + BN_EPS) + bb.z, 0.f);
  }
  {
    float mean = sm.w * inv, var = sq.w * inv - mean * mean;
    h.w = fmaxf(gg.w * (y.w - mean) * rsqrtf(var + BN_EPS) + bb.w, 0.f);
  }
  *(float4*)&out[((size_t)r * 16 + 15) * 512 + o] = h;
}

extern "C" void kernel_launch(void* const* d_in, const int* in_sizes, int n_in,
                              void* d_out, int out_size, void* d_ws, size_t ws_size,
                              hipStream_t stream) {
  const float* pf = (const float*)d_in[0];
  const float* bboxes = (const float*)d_in[1];
  const float* w1 = (const float*)d_in[2];
  const float* b1 = (const float*)d_in[3];
  const float* g1 = (const float*)d_in[4];
  const float* be1 = (const float*)d_in[5];
  const float* w2 = (const float*)d_in[6];
  const float* b2 = (const float*)d_in[7];
  const float* g2 = (const float*)d_in[8];
  const float* be2 = (const float*)d_in[9];
  float* out = (float*)d_out;

  // workspace layout (~13 MB)
  ushort* wb = (ushort*)d_ws;           // 524288 bf16 (w1|w2)
  ushort* Zb = wb + 524288;             // 2097152 bf16 (Z)
  float* Yb = (float*)(Zb + 2097152);   // 2097152 f32 (Y, reused both layers)
  float* stats = Yb + 2097152;          // 2048 f32: [sum1|sq1|sum2|sq2]
  float* sum1 = stats;
  float* sq1 = stats + 512;
  float* sum2 = stats + 1024;
  float* sq2 = stats + 1536;

  // 1: dense copy + w->bf16 + zero stats (t=15 rows overwritten by k_norm later)
  k_copy_prep<<<10240, 256, 0, stream>>>((const float4*)pf, (float4*)out, w1, w2, wb, stats);

  // layer 1: X = pf[:, :, 15, :] (base offset 15*512, row stride 16*512)
  k_agg<<<dim3(64, 4), 256, 0, stream>>>(pf + 7680, 8192, bboxes, stats, g1, be1, 0, Zb);
  k_gemm<<<dim3(64, 8), 256, 0, stream>>>(Zb, wb, b1, Yb, sum1, sq1);

  // layer 2: X = BN1(Yb) inline (stats1 final after gemm1 dispatch boundary)
  k_agg<<<dim3(64, 4), 256, 0, stream>>>(Yb, 512, bboxes, stats, g1, be1, 1, Zb);
  k_gemm<<<dim3(64, 8), 256, 0, stream>>>(Zb, wb + 262144, b2, Yb, sum2, sq2);

  // final BN -> out t=15 slice
  k_norm<<<2048, 256, 0, stream>>>(Yb, sum2, sq2, g2, be2, out);
}